// Round 1
// 380.382 us; speedup vs baseline: 1.0701x; 1.0701x over previous
//
#include <hip/hip_runtime.h>
#include <hip/hip_bf16.h>

typedef __attribute__((ext_vector_type(8))) short bf16x8;   // 8 bf16 in 4 VGPRs (MFMA A/B frag)
typedef __attribute__((ext_vector_type(4))) float f32x4;    // MFMA C/D frag

__device__ __forceinline__ unsigned short f2bf(float f) {   // RNE fp32->bf16
    unsigned u = __float_as_uint(f);
    u += 0x7fff + ((u >> 16) & 1);
    return (unsigned short)(u >> 16);
}
__device__ __forceinline__ float bf2f(unsigned short s) {
    return __uint_as_float(((unsigned)s) << 16);
}

#define GL2LDS16(g, l) __builtin_amdgcn_global_load_lds(                      \
        (const __attribute__((address_space(1))) void*)(g),                   \
        (__attribute__((address_space(3))) void*)(l), 16, 0, 0)

// ---------------- fused setup: degree count + W2 transpose + x->bf16 ----------------

__global__ __launch_bounds__(256) void fused_misc_kernel(
        const int* __restrict__ dst, int* __restrict__ cnt, int e,
        const float* __restrict__ W2, unsigned short* __restrict__ Wt2,
        const float* __restrict__ x, unsigned short* __restrict__ xb, int n4,
        int CB, int TB) {
    int b = blockIdx.x;
    if (b < CB) {
        int i = b * 256 + threadIdx.x;
        if (i < e) atomicAdd(&cnt[dst[i]], 1);
    } else if (b < CB + TB) {
        int i = (b - CB) * 256 + threadIdx.x;   // 0..65535
        int k = i >> 8, n = i & 255;
        Wt2[(size_t)n * 256 + k] = f2bf(W2[i]);
    } else {
        int i = (b - CB - TB) * 256 + threadIdx.x;
        if (i < n4) {
            float4 v = ((const float4*)x)[i];
            ushort4 o;
            o.x = f2bf(v.x); o.y = f2bf(v.y); o.z = f2bf(v.z); o.w = f2bf(v.w);
            ((ushort4*)xb)[i] = o;
        }
    }
}

// ---------------- fold Wf = W_in @ W1  (bf16, transposed [n][k]) and bv = b_in @ W1 ----------------

__global__ __launch_bounds__(256) void wfuse_kernel(const float* __restrict__ W_in, // [128][256]
                                                    const float* __restrict__ b_in, // [256]
                                                    const float* __restrict__ W1,   // [256][256]
                                                    unsigned short* __restrict__ WfT, // [256][128]
                                                    float* __restrict__ bv) {       // [256]
    __shared__ float row[256];
    int k = blockIdx.x;        // 0..127 -> WfT row k ; 128 -> bv
    int n = threadIdx.x;
    row[n] = (k < 128) ? W_in[k * 256 + n] : b_in[n];
    __syncthreads();
    float acc = 0.f;
    #pragma unroll 4
    for (int j = 0; j < 256; ++j) acc = fmaf(row[j], W1[j * 256 + n], acc);
    if (k < 128) WfT[(size_t)n * 128 + k] = f2bf(acc);
    else bv[n] = acc;
}

// ---------------- CSR scan (2-dispatch: block sums, then scatter w/ inline prefix) ----------------

__global__ __launch_bounds__(256) void block_sum_kernel(const int* __restrict__ cnt,
                                                        int* __restrict__ bsums, int n) {
    int tid = threadIdx.x;
    int i = blockIdx.x * 256 + tid;
    int v = (i < n) ? cnt[i] : 0;
    #pragma unroll
    for (int off = 32; off > 0; off >>= 1) v += __shfl_down(v, off);
    __shared__ int ws[4];
    if ((tid & 63) == 0) ws[tid >> 6] = v;
    __syncthreads();
    if (tid == 0) bsums[blockIdx.x] = ws[0] + ws[1] + ws[2] + ws[3];
}

__global__ __launch_bounds__(256) void scatter_scan_kernel(const int* __restrict__ cnt,
                                                           const int* __restrict__ bsums,
                                                           int* __restrict__ offsets,
                                                           int* __restrict__ cursor,
                                                           float* __restrict__ dinv,
                                                           int n, int nb) {
    int tid = threadIdx.x;
    int lane = tid & 63, wid = tid >> 6;
    __shared__ int ws[4], wp[4];

    int bv = (tid < nb && tid < (int)blockIdx.x) ? bsums[tid] : 0;
    int br = bv;
    #pragma unroll
    for (int off = 32; off > 0; off >>= 1) br += __shfl_down(br, off);
    if (lane == 0) wp[wid] = br;

    int i = blockIdx.x * 256 + tid;
    int v = (i < n) ? cnt[i] : 0;
    int s = v;
    #pragma unroll
    for (int off = 1; off < 64; off <<= 1) {
        int t = __shfl_up(s, off);
        if (lane >= off) s += t;
    }
    if (lane == 63) ws[wid] = s;
    __syncthreads();
    int wo = 0;
    #pragma unroll
    for (int k = 0; k < 4; ++k) wo += (k < wid) ? ws[k] : 0;
    int bpref = wp[0] + wp[1] + wp[2] + wp[3];
    int excl = bpref + wo + s - v;
    if (i <= n) { offsets[i] = excl; }
    if (i < n) {
        cursor[i] = excl;
        dinv[i] = rsqrtf((float)v + 1.0f);
    }
}

__global__ void fill_kernel(const int* __restrict__ src, const int* __restrict__ dst,
                            int* __restrict__ cursor, int* __restrict__ csr, int e) {
    int i = blockIdx.x * blockDim.x + threadIdx.x;
    if (i < e) {
        int p = atomicAdd(&cursor[dst[i]], 1);
        csr[p] = src[i];
    }
}

// ---------------- bf16 MFMA GEMM: C[M,256] = A[M,K] @ W[K,256], BK=64 ----------------
// MODE 0: +bias[col]   MODE 1: *dinv[row]   MODE 2: relu(acc + s[row]*bv[col] + b[col])

template <int MODE>
__global__ __launch_bounds__(256) void gemm_bf16(const unsigned short* __restrict__ A,
                                                 const unsigned short* __restrict__ Wt,
                                                 const float* __restrict__ aux,
                                                 const float* __restrict__ aux2,
                                                 const float* __restrict__ aux3,
                                                 unsigned short* __restrict__ C,
                                                 int M, int K) {
    __shared__ unsigned short As[128 * 64];   // [row][k] 16 KB
    __shared__ unsigned short Bs[128 * 64];   // [col][k] 16 KB
    const int tid  = threadIdx.x;
    const int lane = tid & 63;
    const int w    = tid >> 6;
    const int wr   = w >> 1, wc = w & 1;
    const int row0 = blockIdx.x * 128;
    const int col0 = blockIdx.y * 128;
    const int mlane = lane & 15, quad = lane >> 4;

    f32x4 acc[4][4];
    #pragma unroll
    for (int i = 0; i < 4; ++i)
        #pragma unroll
        for (int j = 0; j < 4; ++j) acc[i][j] = f32x4{0.f, 0.f, 0.f, 0.f};

    const unsigned short* gA[4]; const unsigned short* gB[4];
    unsigned short* lA[4]; unsigned short* lB[4];
    #pragma unroll
    for (int p = 0; p < 4; ++p) {
        int cid = (p * 4 + w) * 64 + lane;
        int row = cid >> 3, slot = cid & 7;
        int rowA = row0 + row; if (rowA >= M) rowA = M - 1;
        gA[p] = A + (size_t)rowA * K + slot * 8;
        gB[p] = Wt + (size_t)(col0 + row) * K + slot * 8;
        lA[p] = &As[((p * 4 + w) * 64) * 8];
        lB[p] = &Bs[((p * 4 + w) * 64) * 8];
    }

    for (int k0 = 0; k0 < K; k0 += 64) {
        #pragma unroll
        for (int p = 0; p < 4; ++p) GL2LDS16(gA[p] + k0, lA[p]);
        #pragma unroll
        for (int p = 0; p < 4; ++p) GL2LDS16(gB[p] + k0, lB[p]);
        __syncthreads();
        #pragma unroll
        for (int ks = 0; ks < 2; ++ks) {
            bf16x8 af[4], bfv[4];
            #pragma unroll
            for (int i = 0; i < 4; ++i)
                af[i] = *(const bf16x8*)&As[(wr * 64 + i * 16 + mlane) * 64 + ks * 32 + quad * 8];
            #pragma unroll
            for (int j = 0; j < 4; ++j)
                bfv[j] = *(const bf16x8*)&Bs[(wc * 64 + j * 16 + mlane) * 64 + ks * 32 + quad * 8];
            #pragma unroll
            for (int i = 0; i < 4; ++i)
                #pragma unroll
                for (int j = 0; j < 4; ++j)
                    acc[i][j] = __builtin_amdgcn_mfma_f32_16x16x32_bf16(af[i], bfv[j], acc[i][j], 0, 0, 0);
        }
        __syncthreads();
    }

    float bj[4], cj[4];
    if (MODE == 0) {
        #pragma unroll
        for (int j = 0; j < 4; ++j) bj[j] = aux[col0 + wc * 64 + j * 16 + mlane];
    } else if (MODE == 2) {
        #pragma unroll
        for (int j = 0; j < 4; ++j) {
            int gcol = col0 + wc * 64 + j * 16 + mlane;
            bj[j] = aux2[gcol];
            cj[j] = aux3[gcol];
        }
    }
    #pragma unroll
    for (int i = 0; i < 4; ++i) {
        #pragma unroll
        for (int r = 0; r < 4; ++r) {
            int grow = row0 + wr * 64 + i * 16 + quad * 4 + r;
            if (grow < M) {
                float d = (MODE != 0) ? aux[grow] : 0.f;
                #pragma unroll
                for (int j = 0; j < 4; ++j) {
                    int gcol = col0 + wc * 64 + j * 16 + mlane;
                    float v = acc[i][j][r];
                    if (MODE == 0)      v = v + bj[j];
                    else if (MODE == 1) v = v * d;
                    else {              v = fmaf(d, bj[j], v) + cj[j]; v = fmaxf(v, 0.f); }
                    C[(size_t)grow * 256 + gcol] = f2bf(v);
                }
            }
        }
    }
}

// ---------------- layer-1 aggregation over raw x (128-wide), dinv-weighted gather ----------------
// ax[i] = dinv[i] * ( sum_{src in N(i)} dinv[src]*x[src] + dinv[i]*x[i] )
// s[i]  = dinv[i] * ( sum_{src in N(i)} dinv[src] + dinv[i] )

__global__ __launch_bounds__(256) void agg_x_kernel(const unsigned short* __restrict__ xb,
                                                    const int* __restrict__ offsets,
                                                    const int* __restrict__ csr,
                                                    const float* __restrict__ dinv,
                                                    unsigned short* __restrict__ ax,
                                                    float* __restrict__ s_out, int n) {
    int node = blockIdx.x * 4 + (threadIdx.x >> 6);
    if (node >= n) return;
    int lane = threadIdx.x & 63;
    int half = lane >> 5, hl = lane & 31;
    const ushort4* x4 = (const ushort4*)xb;   // 32 ushort4 per 128-wide row
    int beg = offsets[node], end = offsets[node + 1];
    float dn = dinv[node];
    float a0 = 0.f, a1 = 0.f, a2 = 0.f, a3 = 0.f;
    float sdl = 0.f;
    int e = beg;
    while (e < end) {
        int cnt = end - e; if (cnt > 64) cnt = 64;
        int myi = 0; float mydv = 0.f;
        if (lane < cnt) { myi = csr[e + lane]; mydv = dinv[myi]; sdl += mydv; }
        int j = 0;
        for (; j + 8 <= cnt; j += 8) {
            int s0 = __shfl(myi, j + half),     s1 = __shfl(myi, j + 2 + half);
            int s2 = __shfl(myi, j + 4 + half), s3 = __shfl(myi, j + 6 + half);
            float d0 = __shfl(mydv, j + half),     d1 = __shfl(mydv, j + 2 + half);
            float d2 = __shfl(mydv, j + 4 + half), d3 = __shfl(mydv, j + 6 + half);
            ushort4 v0 = x4[(size_t)s0 * 32 + hl];
            ushort4 v1 = x4[(size_t)s1 * 32 + hl];
            ushort4 v2 = x4[(size_t)s2 * 32 + hl];
            ushort4 v3 = x4[(size_t)s3 * 32 + hl];
            a0 = fmaf(bf2f(v0.x), d0, a0); a1 = fmaf(bf2f(v0.y), d0, a1);
            a2 = fmaf(bf2f(v0.z), d0, a2); a3 = fmaf(bf2f(v0.w), d0, a3);
            a0 = fmaf(bf2f(v1.x), d1, a0); a1 = fmaf(bf2f(v1.y), d1, a1);
            a2 = fmaf(bf2f(v1.z), d1, a2); a3 = fmaf(bf2f(v1.w), d1, a3);
            a0 = fmaf(bf2f(v2.x), d2, a0); a1 = fmaf(bf2f(v2.y), d2, a1);
            a2 = fmaf(bf2f(v2.z), d2, a2); a3 = fmaf(bf2f(v2.w), d2, a3);
            a0 = fmaf(bf2f(v3.x), d3, a0); a1 = fmaf(bf2f(v3.y), d3, a1);
            a2 = fmaf(bf2f(v3.z), d3, a2); a3 = fmaf(bf2f(v3.w), d3, a3);
        }
        for (; j < cnt; j += 2) {
            int jj = j + half; int sel = (jj < cnt) ? jj : j;
            int s_ = __shfl(myi, sel);
            float dd = __shfl(mydv, sel);
            if (jj >= cnt) dd = 0.f;
            ushort4 v = x4[(size_t)s_ * 32 + hl];
            a0 = fmaf(bf2f(v.x), dd, a0); a1 = fmaf(bf2f(v.y), dd, a1);
            a2 = fmaf(bf2f(v.z), dd, a2); a3 = fmaf(bf2f(v.w), dd, a3);
        }
        e += cnt;
    }
    a0 += __shfl_xor(a0, 32); a1 += __shfl_xor(a1, 32);
    a2 += __shfl_xor(a2, 32); a3 += __shfl_xor(a3, 32);
    float sd = sdl;
    #pragma unroll
    for (int off = 32; off > 0; off >>= 1) sd += __shfl_down(sd, off);
    if (lane < 32) {
        ushort4 sv = x4[(size_t)node * 32 + hl];
        a0 = fmaf(dn, bf2f(sv.x), a0) * dn;
        a1 = fmaf(dn, bf2f(sv.y), a1) * dn;
        a2 = fmaf(dn, bf2f(sv.z), a2) * dn;
        a3 = fmaf(dn, bf2f(sv.w), a3) * dn;
        ushort4 r;
        r.x = f2bf(a0); r.y = f2bf(a1); r.z = f2bf(a2); r.w = f2bf(a3);
        ((ushort4*)ax)[(size_t)node * 32 + hl] = r;
        if (lane == 0) s_out[node] = dn * (sd + dn);
    }
}

// ---------------- aggregation: index broadcast + 8-deep gather MLP (layer 2, 256-wide) ----------------

__global__ __launch_bounds__(256) void agg_kernel(const unsigned short* __restrict__ hs,
                                                  const int* __restrict__ offsets,
                                                  const int* __restrict__ csr,
                                                  const float* __restrict__ dinv,
                                                  const float* __restrict__ bias,
                                                  unsigned short* __restrict__ out, int n) {
    int node = blockIdx.x * 4 + (threadIdx.x >> 6);
    if (node >= n) return;
    int lane = threadIdx.x & 63;
    const ushort4* hs4 = (const ushort4*)hs;
    int beg = offsets[node], end = offsets[node + 1];
    ushort4 sv = hs4[(size_t)node * 64 + lane];
    float a0 = bf2f(sv.x), a1 = bf2f(sv.y), a2 = bf2f(sv.z), a3 = bf2f(sv.w);
    float c0 = 0.f, c1 = 0.f, c2 = 0.f, c3 = 0.f;

    int e = beg;
    while (e < end) {
        int cnt = end - e; if (cnt > 64) cnt = 64;
        int myi = (lane < cnt) ? csr[e + lane] : 0;
        int j = 0;
        for (; j + 8 <= cnt; j += 8) {
            int s0 = __shfl(myi, j + 0), s1 = __shfl(myi, j + 1);
            int s2 = __shfl(myi, j + 2), s3 = __shfl(myi, j + 3);
            int s4 = __shfl(myi, j + 4), s5 = __shfl(myi, j + 5);
            int s6 = __shfl(myi, j + 6), s7 = __shfl(myi, j + 7);
            ushort4 v0 = hs4[(size_t)s0 * 64 + lane];
            ushort4 v1 = hs4[(size_t)s1 * 64 + lane];
            ushort4 v2 = hs4[(size_t)s2 * 64 + lane];
            ushort4 v3 = hs4[(size_t)s3 * 64 + lane];
            ushort4 v4 = hs4[(size_t)s4 * 64 + lane];
            ushort4 v5 = hs4[(size_t)s5 * 64 + lane];
            ushort4 v6 = hs4[(size_t)s6 * 64 + lane];
            ushort4 v7 = hs4[(size_t)s7 * 64 + lane];
            a0 += bf2f(v0.x) + bf2f(v1.x) + bf2f(v2.x) + bf2f(v3.x);
            a1 += bf2f(v0.y) + bf2f(v1.y) + bf2f(v2.y) + bf2f(v3.y);
            a2 += bf2f(v0.z) + bf2f(v1.z) + bf2f(v2.z) + bf2f(v3.z);
            a3 += bf2f(v0.w) + bf2f(v1.w) + bf2f(v2.w) + bf2f(v3.w);
            c0 += bf2f(v4.x) + bf2f(v5.x) + bf2f(v6.x) + bf2f(v7.x);
            c1 += bf2f(v4.y) + bf2f(v5.y) + bf2f(v6.y) + bf2f(v7.y);
            c2 += bf2f(v4.z) + bf2f(v5.z) + bf2f(v6.z) + bf2f(v7.z);
            c3 += bf2f(v4.w) + bf2f(v5.w) + bf2f(v6.w) + bf2f(v7.w);
        }
        for (; j < cnt; ++j) {
            int s = __shfl(myi, j);
            ushort4 v = hs4[(size_t)s * 64 + lane];
            a0 += bf2f(v.x); a1 += bf2f(v.y); a2 += bf2f(v.z); a3 += bf2f(v.w);
        }
        e += cnt;
    }
    a0 += c0; a1 += c1; a2 += c2; a3 += c3;

    float d = dinv[node];
    float4 b = ((const float4*)bias)[lane];
    ushort4 r;
    r.x = f2bf(fmaxf(fmaf(a0, d, b.x), 0.f));
    r.y = f2bf(fmaxf(fmaf(a1, d, b.y), 0.f));
    r.z = f2bf(fmaxf(fmaf(a2, d, b.z), 0.f));
    r.w = f2bf(fmaxf(fmaf(a3, d, b.w), 0.f));
    ((ushort4*)out)[(size_t)node * 64 + lane] = r;
}

// ---------------- pooling (known-good split) ----------------

__global__ __launch_bounds__(256) void pool_partial_kernel(const unsigned short* __restrict__ h,
                                                           const int* __restrict__ batch,
                                                           float* __restrict__ sums,
                                                           int* __restrict__ counts,
                                                           int n, int chunk) {
    int beg = blockIdx.x * chunk;
    int end = beg + chunk; if (end > n) end = n;
    if (beg >= end) return;
    int c = threadIdx.x;
    int curg = batch[beg];
    float acc = 0.f;
    int runlen = 0;
    for (int i = beg; i < end; ++i) {
        int g = batch[i];
        if (g != curg) {
            atomicAdd(&sums[(size_t)curg * 256 + c], acc);
            if (c == 0) atomicAdd(&counts[curg], runlen);
            acc = 0.f; runlen = 0; curg = g;
        }
        acc += bf2f(h[(size_t)i * 256 + c]);
        ++runlen;
    }
    atomicAdd(&sums[(size_t)curg * 256 + c], acc);
    if (c == 0) atomicAdd(&counts[curg], runlen);
}

__global__ __launch_bounds__(256) void pool_final_kernel(const float* __restrict__ sums,
                                                         const int* __restrict__ counts,
                                                         const float* __restrict__ Wout,
                                                         const float* __restrict__ bout,
                                                         float* __restrict__ out) {
    __shared__ float pl[256];
    int g = blockIdx.x;
    int c = threadIdx.x;
    int cnt = counts[g];
    pl[c] = sums[(size_t)g * 256 + c] / (float)(cnt > 0 ? cnt : 1);
    __syncthreads();
    if (c < 16) {
        float o = bout[c];
        #pragma unroll 4
        for (int k = 0; k < 256; ++k) o = fmaf(pl[k], Wout[k * 16 + c], o);
        out[g * 16 + c] = o;
    }
}

// ---------------- launch ----------------

extern "C" void kernel_launch(void* const* d_in, const int* in_sizes, int n_in,
                              void* d_out, int out_size, void* d_ws, size_t ws_size,
                              hipStream_t stream) {
    const float* x     = (const float*)d_in[0];
    const int*   ei    = (const int*)d_in[1];
    const int*   batch = (const int*)d_in[2];
    const float* W_in  = (const float*)d_in[3];
    const float* b_in  = (const float*)d_in[4];
    const float* W1    = (const float*)d_in[5];
    const float* b1    = (const float*)d_in[6];
    const float* W2    = (const float*)d_in[7];
    const float* b2    = (const float*)d_in[8];
    const float* Wout  = (const float*)d_in[9];
    const float* bout  = (const float*)d_in[10];

    const int E = in_sizes[1] / 2;
    const int N = in_sizes[2];
    const int IN_DIM = in_sizes[0] / N;   // 128
    const int G = 128;
    const int* src = ei;
    const int* dst = ei + E;

    char* ws = (char*)d_ws;
    size_t off = 0;
    auto alloc = [&](size_t bytes) { size_t p = off; off += (bytes + 255) & ~(size_t)255; return p; };
    unsigned short* bufA = (unsigned short*)(ws + alloc((size_t)N * 256 * 2));
    unsigned short* bufB = (unsigned short*)(ws + alloc((size_t)N * 256 * 2));
    unsigned short* xb   = (unsigned short*)(ws + alloc((size_t)N * IN_DIM * 2));
    unsigned short* Wt2  = (unsigned short*)(ws + alloc((size_t)256 * 256 * 2));
    unsigned short* WfT  = (unsigned short*)(ws + alloc((size_t)256 * IN_DIM * 2));
    float*          bv   = (float*)(ws + alloc((size_t)256 * 4));
    float*          sbuf = (float*)(ws + alloc((size_t)N * 4));
    size_t zbeg = off;
    int*   deg_cnt = (int*)(ws + alloc((size_t)N * 4));
    float* sums    = (float*)(ws + alloc((size_t)G * 256 * 4));
    int*   counts  = (int*)(ws + alloc((size_t)G * 4));
    size_t zend = off;
    float* dinv    = (float*)(ws + alloc((size_t)N * 4));
    int*   offsets = (int*)(ws + alloc((size_t)(N + 1) * 4));
    int*   cursor  = (int*)(ws + alloc((size_t)N * 4));
    int*   csr     = (int*)(ws + alloc((size_t)E * 4));
    int*   bsums   = (int*)(ws + alloc((size_t)256 * 4));
    (void)ws_size;

    // ax (layer-1 aggregated x, [N,128] bf16) aliases bufB: bufB is dead until the
    // layer-2 gemm writes it, and gemm<2> reads ax while writing bufA. No overlap.
    unsigned short* axb = bufB;

    const int NB  = (N + 255) / 256;
    const int NB1 = (N + 1 + 255) / 256;
    const int CB  = (E + 255) / 256;
    const int TB  = (256 * 256 + 255) / 256;
    const int XB  = (N * IN_DIM / 4 + 255) / 256;

    hipMemsetAsync(ws + zbeg, 0, zend - zbeg, stream);
    fused_misc_kernel<<<CB + TB + XB, 256, 0, stream>>>(
        dst, deg_cnt, E, W2, Wt2, x, xb, N * IN_DIM / 4, CB, TB);
    wfuse_kernel<<<129, 256, 0, stream>>>(W_in, b_in, W1, WfT, bv);
    block_sum_kernel<<<NB, 256, 0, stream>>>(deg_cnt, bsums, N);
    scatter_scan_kernel<<<NB1, 256, 0, stream>>>(deg_cnt, bsums, offsets, cursor, dinv, N, NB);
    fill_kernel<<<(E + 255) / 256, 256, 0, stream>>>(src, dst, cursor, csr, E);

    // layer 1: aggregate raw x (128-wide), then one fused GEMM with relu epilogue
    agg_x_kernel<<<(N + 3) / 4, 256, 0, stream>>>(xb, offsets, csr, dinv, axb, sbuf, N);
    dim3 gg((N + 127) / 128, 2);
    gemm_bf16<2><<<gg, 256, 0, stream>>>(axb, WfT, sbuf, bv, b1, bufA, N, IN_DIM);

    // layer 2: gemm (dinv-scaled) then 256-wide aggregation with relu+bias
    gemm_bf16<1><<<gg, 256, 0, stream>>>(bufA, Wt2, dinv, nullptr, nullptr, bufB, N, 256);
    agg_kernel<<<(N + 3) / 4, 256, 0, stream>>>(bufB, offsets, csr, dinv, b2, bufA, N);

    const int PBLOCKS = 512;
    int chunk = (N + PBLOCKS - 1) / PBLOCKS;
    pool_partial_kernel<<<PBLOCKS, 256, 0, stream>>>(bufA, batch, sums, counts, N, chunk);
    pool_final_kernel<<<G, 256, 0, stream>>>(sums, counts, Wout, bout, (float*)d_out);
}